// Round 7
// baseline (264.069 us; speedup 1.0000x reference)
//
#include <hip/hip_runtime.h>
#include <stdint.h>

#define GLOBAL_AS __attribute__((address_space(1)))
#define LDS_AS __attribute__((address_space(3)))

namespace {
constexpr int Bn = 8, Sn = 1024, Hn = 16, Dn = 64, Mn = 1024;
constexpr int BQ = 128;                 // queries per block (64 per wave, 2 waves)
constexpr int TK = 64;                  // keys per tile
constexpr int NT = Sn / TK;             // 16 tiles
constexpr int LDE = 72;                 // padded leading dim (shorts); 144B rows -> 16B aligned
constexpr int TILE_SH = 2 * 64 * LDE;   // shorts per (K | Vt) tile = 9216 (18432 B)
constexpr size_t BLOB_BYTES = (size_t)Bn * Hn * NT * TILE_SH * 2;   // 37,748,736
constexpr size_t ROWM_OFF = BLOB_BYTES;                             // 8192 B (rowm) + 1024 B (colbits)
constexpr float kSC = 0.125f * 1.4426950408889634f;  // 1/sqrt(D) * log2(e) folded into Q

using f32x16 = __attribute__((ext_vector_type(16))) float;
using s16x4 = __attribute__((ext_vector_type(4))) short;
using s16x8 = __attribute__((ext_vector_type(8))) short;

// RNE f32->bf16 pair pack; native __bf16 cast lowers to v_cvt_pk_bf16_f32 on gfx950
__device__ inline unsigned pk2(float a, float b) {
    union { __bf16 h[2]; unsigned u; } x;
    x.h[0] = (__bf16)a; x.h[1] = (__bf16)b;
    return x.u;
}

#if __has_builtin(__builtin_amdgcn_exp2f)
#define EXP2F __builtin_amdgcn_exp2f
#else
#define EXP2F exp2f
#endif
}  // namespace

// ---------------- precompute: bf16 K (row-major) + V^T tiles, LDS-image format ----------------
__global__ __launch_bounds__(256) void convert2(
    const float* __restrict__ K, const float* __restrict__ V,
    unsigned short* __restrict__ blob)
{
    __shared__ float Vl[64 * 65];   // f32 transpose buffer, stride 65 words
    const int t = threadIdx.x;
    const int kt = blockIdx.x, h = blockIdx.y, b = blockIdx.z;
    unsigned short* out = blob + ((size_t)((b * Hn + h) * NT + kt)) * TILE_SH;

    const int key = t >> 2, dg = (t & 3) * 16;
    {   // K tile rows [key][d], bf16
        const float* kp = K + (((size_t)b * Sn + kt * TK + key) * Hn + h) * Dn + dg;
        uint2 w[4];
        #pragma unroll
        for (int j = 0; j < 4; ++j) {
            float4 v = *(const float4*)(kp + j * 4);
            w[j].x = pk2(v.x, v.y); w[j].y = pk2(v.z, v.w);
        }
        uint2* o = (uint2*)&out[key * LDE + dg];
        #pragma unroll
        for (int j = 0; j < 4; ++j) o[j] = w[j];
    }
    {   // V rows -> f32 LDS transposed
        const float* vp = V + (((size_t)b * Hn + h) * Sn + kt * TK + key) * Dn + dg;
        #pragma unroll
        for (int j = 0; j < 4; ++j) {
            float4 v = *(const float4*)(vp + j * 4);
            Vl[(dg + j * 4 + 0) * 65 + key] = v.x;
            Vl[(dg + j * 4 + 1) * 65 + key] = v.y;
            Vl[(dg + j * 4 + 2) * 65 + key] = v.z;
            Vl[(dg + j * 4 + 3) * 65 + key] = v.w;
        }
    }
    __syncthreads();
    {   // V^T rows [d][key] -> bf16 blob
        const int d = t >> 2, kc = (t & 3) * 16;
        float tmp[16];
        #pragma unroll
        for (int i = 0; i < 16; ++i) tmp[i] = Vl[d * 65 + kc + i];
        uint2* o = (uint2*)&out[64 * LDE + d * LDE + kc];
        #pragma unroll
        for (int j = 0; j < 4; ++j) {
            uint2 w; w.x = pk2(tmp[j * 4 + 0], tmp[j * 4 + 1]);
            w.y = pk2(tmp[j * 4 + 2], tmp[j * 4 + 3]);
            o[j] = w;
        }
    }
}

// ---------------- masks: zero ALL 2304 u32 (rowm 2048 + colbits 256), then fill ----------------
__global__ __launch_bounds__(1024) void masks_k(
    const int* __restrict__ qmb, const int* __restrict__ qms,
    const int* __restrict__ kmb, const int* __restrict__ kms,
    unsigned int* __restrict__ wsm)
{
    const int t = threadIdx.x;
    wsm[t] = 0; wsm[t + 1024] = 0;
    if (t < 256) wsm[t + 2048] = 0;
    __syncthreads();
    unsigned char* rowm = (unsigned char*)wsm;
    unsigned long long* colbits = (unsigned long long*)(wsm + 2048);
    rowm[qmb[t] * Sn + qms[t]] = 1;
    atomicOr(&colbits[kmb[t] * NT + (kms[t] >> 6)], 1ull << (kms[t] & 63));
}

// ---------------- main kernel: S^T = K·Q^T (32x32x16), P chained in-register into P·V ----------------
// sigma-cancellation: P keeps its natural C-layout key enumeration; V B-frags are
// loaded with the IDENTICAL enumeration, so the hardware k-slot mapping cancels.
// Double-buffered staging: ONE barrier per iteration; its implicit vmcnt(0) drain
// waits on loads issued a full compute-iteration earlier (near-free).
__global__ __launch_bounds__(128, 2) void attn3(
    const float* __restrict__ Q, const unsigned short* __restrict__ blob,
    const unsigned char* __restrict__ rowm,
    const unsigned long long* __restrict__ colbits,
    float* __restrict__ Out)
{
    __shared__ unsigned short KV2[2][TILE_SH];   // double-buffered [K 64x72 | Vt 64x72]
    __shared__ float Ls[2][2][32];               // [wave][sub][q]: 1/lsum
    const int t = threadIdx.x;
    const int wave = t >> 6, lane = t & 63;
    const int l31 = lane & 31, q2 = lane >> 5;
    const int bh = blockIdx.x, b = bh >> 4, h = bh & 15;
    const int qb = blockIdx.y * BQ + wave * 64;   // this wave's 64 queries

    const unsigned short* tile0 = blob + (size_t)bh * NT * TILE_SH;

    // issue tile-0 staging first; Q-preamble compute hides its latency
    {
        const GLOBAL_AS unsigned int* g = (const GLOBAL_AS unsigned int*)tile0;
        LDS_AS unsigned int* l = (LDS_AS unsigned int*)&KV2[0][0];
        #pragma unroll
        for (int j = 0; j < 9; ++j)
            __builtin_amdgcn_global_load_lds(g + (j * 2048 + t * 16) / 4,
                                             l + (j * 2048 + t * 16) / 4, 16, 0, 0);
    }

    // Q B-fragments: B[k=d][n=q], lane n=l31, slot (q2,j) -> d = st*16 + q2*8 + j
    s16x8 qf[2][4];
    float rmONE[2];
    unsigned rmKEEP[2];
    #pragma unroll
    for (int sub = 0; sub < 2; ++sub) {
        const float* qp = Q + (((size_t)b * Sn + qb + sub * 32 + l31) * Hn + h) * Dn + q2 * 8;
        #pragma unroll
        for (int st = 0; st < 4; ++st) {
            float4 a = *(const float4*)(qp + st * 16);
            float4 c = *(const float4*)(qp + st * 16 + 4);
            union { unsigned w[4]; s16x8 v; } f;
            f.w[0] = pk2(a.x * kSC, a.y * kSC);
            f.w[1] = pk2(a.z * kSC, a.w * kSC);
            f.w[2] = pk2(c.x * kSC, c.y * kSC);
            f.w[3] = pk2(c.z * kSC, c.w * kSC);
            qf[sub][st] = f.v;
        }
        const bool rmb = rowm[b * Sn + qb + sub * 32 + l31] != 0;
        rmONE[sub] = rmb ? 1.0f : 0.0f;
        rmKEEP[sub] = rmb ? 0u : 0xFFFFFFFFu;
    }

    f32x16 O[2][2];
    #pragma unroll
    for (int sub = 0; sub < 2; ++sub)
        #pragma unroll
        for (int dt = 0; dt < 2; ++dt)
            #pragma unroll
            for (int i = 0; i < 16; ++i) O[sub][dt][i] = 0.0f;
    float lsum[2] = {0.0f, 0.0f};

    for (int kt = 0; kt < NT; ++kt) {
        const int cur = kt & 1;
        // ONE barrier: (a) all waves done reading buf[cur^1] from iter kt-1 (safe to
        // overwrite), (b) vmcnt drain of buf[cur] loads issued at iter kt-1 top.
        __syncthreads();
        if (kt + 1 < NT) {   // stage next tile into the other buffer (block-uniform branch)
            const GLOBAL_AS unsigned int* g =
                (const GLOBAL_AS unsigned int*)(tile0 + (size_t)(kt + 1) * TILE_SH);
            LDS_AS unsigned int* l = (LDS_AS unsigned int*)&KV2[cur ^ 1][0];
            #pragma unroll
            for (int j = 0; j < 9; ++j)
                __builtin_amdgcn_global_load_lds(g + (j * 2048 + t * 16) / 4,
                                                 l + (j * 2048 + t * 16) / 4, 16, 0, 0);
        }
        const unsigned short* Kl = &KV2[cur][0];
        const unsigned short* Vt = &KV2[cur][64 * LDE];
        const unsigned long long cmask = colbits[b * NT + kt];

        #pragma unroll
        for (int ct = 0; ct < 2; ++ct) {
            // K A-frags: A[m=key][k=d], lane m = ct*32+l31, slot (q2,j) -> d = st*16+q2*8+j
            s16x8 kf[4];
            #pragma unroll
            for (int st = 0; st < 4; ++st)
                kf[st] = *(const s16x8*)&Kl[(ct * 32 + l31) * LDE + st * 16 + q2 * 8];
            const unsigned ncm = ~(((unsigned)(cmask >> (ct * 32))) >> (q2 * 4));

            s16x8 P[2][2];   // [sub][chunk]: natural-enumeration A-frags for PV
            #pragma unroll
            for (int sub = 0; sub < 2; ++sub) {
                f32x16 sc;
                #pragma unroll
                for (int i = 0; i < 16; ++i) sc[i] = 0.0f;
                #pragma unroll
                for (int st = 0; st < 4; ++st)
                    sc = __builtin_amdgcn_mfma_f32_32x32x16_bf16(kf[st], qf[sub][st], sc, 0, 0, 0);
                // S^T C-layout (HW-verified): key_in_block = (reg&3)+8*(reg>>2)+4*q2, q=l31
                const unsigned keep = ncm & rmKEEP[sub];
                unsigned u[8];
                #pragma unroll
                for (int c = 0; c < 4; ++c) {
                    float p[4];
                    #pragma unroll
                    for (int j = 0; j < 4; ++j) {
                        float e = EXP2F(sc[4 * c + j]);
                        unsigned m = (unsigned)__builtin_amdgcn_sbfe((int)keep, 8 * c + j, 1);
                        p[j] = __uint_as_float(__float_as_uint(e) & m) + rmONE[sub];
                    }
                    lsum[sub] += (p[0] + p[1]) + (p[2] + p[3]);
                    u[2 * c]     = pk2(p[0], p[1]);
                    u[2 * c + 1] = pk2(p[2], p[3]);
                }
                union { unsigned w[4]; s16x8 v; } f0, f1;
                f0.w[0] = u[0]; f0.w[1] = u[1]; f0.w[2] = u[2]; f0.w[3] = u[3];
                f1.w[0] = u[4]; f1.w[1] = u[5]; f1.w[2] = u[6]; f1.w[3] = u[7];
                P[sub][0] = f0.v;   // slot (q2,j') -> key 16*0 + 8*(j'>>2) + 4*q2 + (j'&3)
                P[sub][1] = f1.v;   // slot (q2,j') -> key 16*1 + 8*(j'>>2) + 4*q2 + (j'&3)
            }
            // P·V: B = V^T with the SAME slot->key enumeration as P:
            // slot (q2,j') -> key = ct*32 + ch*16 + 8*(j'>>2) + 4*q2 + (j'&3)
            #pragma unroll
            for (int dt = 0; dt < 2; ++dt)
                #pragma unroll
                for (int ch = 0; ch < 2; ++ch) {
                    const int base = (dt * 32 + l31) * LDE + ct * 32 + ch * 16 + q2 * 4;
                    s16x4 lo = *(const s16x4*)&Vt[base];       // keys +{0..3}
                    s16x4 hi = *(const s16x4*)&Vt[base + 8];   // keys +8+{0..3}
                    s16x8 vf = __builtin_shufflevector(lo, hi, 0, 1, 2, 3, 4, 5, 6, 7);
                    O[0][dt] = __builtin_amdgcn_mfma_f32_32x32x16_bf16(P[0][ch], vf, O[0][dt], 0, 0, 0);
                    O[1][dt] = __builtin_amdgcn_mfma_f32_32x32x16_bf16(P[1][ch], vf, O[1][dt], 0, 0, 0);
                }
        }
    }

    // epilogue: lsum is per q=l31 (half the keys per lane; halves are lanes l, l^32)
    #pragma unroll
    for (int sub = 0; sub < 2; ++sub) {
        float s = lsum[sub] + __shfl_xor(lsum[sub], 32, 64);
        if (lane < 32) Ls[wave][sub][l31] = 1.0f / s;
    }
    __syncthreads();
    float* op = Out + ((size_t)(b * Hn + h)) * Sn * Dn;
    #pragma unroll
    for (int sub = 0; sub < 2; ++sub)
        #pragma unroll
        for (int reg = 0; reg < 16; ++reg) {
            const int qrow = (reg & 3) + 8 * (reg >> 2) + 4 * q2;
            const float invl = Ls[wave][sub][qrow];
            const int q = qb + sub * 32 + qrow;
            #pragma unroll
            for (int dt = 0; dt < 2; ++dt)
                op[(size_t)q * Dn + dt * 32 + l31] = O[sub][dt][reg] * invl;
        }
}

extern "C" void kernel_launch(void* const* d_in, const int* in_sizes, int n_in,
                              void* d_out, int out_size, void* d_ws, size_t ws_size,
                              hipStream_t stream) {
    (void)in_sizes; (void)n_in; (void)out_size; (void)ws_size;
    const float* Q = (const float*)d_in[0];
    const float* K = (const float*)d_in[1];
    const float* V = (const float*)d_in[2];
    const int* qmb = (const int*)d_in[3];
    const int* qms = (const int*)d_in[4];
    const int* kmb = (const int*)d_in[5];
    const int* kms = (const int*)d_in[6];
    float* Out = (float*)d_out;

    unsigned short* blob = (unsigned short*)d_ws;
    unsigned int* wsm = (unsigned int*)(void*)((char*)d_ws + ROWM_OFF);
    const unsigned char* rowm = (const unsigned char*)wsm;
    const unsigned long long* colbits = (const unsigned long long*)(wsm + 2048);

    masks_k<<<1, 1024, 0, stream>>>(qmb, qms, kmb, kms, wsm);
    convert2<<<dim3(NT, Hn, Bn), 256, 0, stream>>>(K, V, blob);
    attn3<<<dim3(Bn * Hn, Sn / BQ), 128, 0, stream>>>(Q, blob, rowm, colbits, Out);
}

// Round 8
// 194.333 us; speedup vs baseline: 1.3588x; 1.3588x over previous
//
#include <hip/hip_runtime.h>
#include <stdint.h>

#define GLOBAL_AS __attribute__((address_space(1)))
#define LDS_AS __attribute__((address_space(3)))

namespace {
constexpr int Bn = 8, Sn = 1024, Hn = 16, Dn = 64, Mn = 1024;
constexpr int BQ = 128;                 // queries per block (32 per wave, 4 waves)
constexpr int TK = 64;                  // keys per tile
constexpr int NT = Sn / TK;             // 16 tiles
constexpr int LDE = 72;                 // padded leading dim (shorts); 144B rows -> 16B aligned
constexpr int TILE_SH = 2 * 64 * LDE;   // shorts per (K | Vt) tile = 9216 (18432 B)
constexpr size_t BLOB_BYTES = (size_t)Bn * Hn * NT * TILE_SH * 2;   // 37,748,736
constexpr size_t ROWM_OFF = BLOB_BYTES;                             // 8192 B (rowm) + 1024 B (colbits)
constexpr float kSC = 0.125f * 1.4426950408889634f;  // 1/sqrt(D) * log2(e) folded into Q

using f32x16 = __attribute__((ext_vector_type(16))) float;
using s16x4 = __attribute__((ext_vector_type(4))) short;
using s16x8 = __attribute__((ext_vector_type(8))) short;

// RNE f32->bf16 pair pack; native __bf16 cast lowers to v_cvt_pk_bf16_f32 on gfx950
__device__ inline unsigned pk2(float a, float b) {
    union { __bf16 h[2]; unsigned u; } x;
    x.h[0] = (__bf16)a; x.h[1] = (__bf16)b;
    return x.u;
}

#if __has_builtin(__builtin_amdgcn_exp2f)
#define EXP2F __builtin_amdgcn_exp2f
#else
#define EXP2F exp2f
#endif
}  // namespace

// ---- precompute: bf16 K (row-major) + V^T tiles (LDS-image format); block 0 also builds masks ----
__global__ __launch_bounds__(256) void convert3(
    const float* __restrict__ K, const float* __restrict__ V,
    unsigned short* __restrict__ blob,
    const int* __restrict__ qmb, const int* __restrict__ qms,
    const int* __restrict__ kmb, const int* __restrict__ kms,
    unsigned int* __restrict__ wsm)
{
    __shared__ float Vl[64 * 65];   // f32 transpose buffer, stride 65 words
    const int t = threadIdx.x;
    const int kt = blockIdx.x, h = blockIdx.y, b = blockIdx.z;

    if (kt == 0 && h == 0 && b == 0) {   // block-uniform branch: masks (zero 2304 u32 + fill)
        #pragma unroll
        for (int i = 0; i < 9; ++i) wsm[t + 256 * i] = 0;
        __syncthreads();
        unsigned char* rowm = (unsigned char*)wsm;
        unsigned long long* colbits = (unsigned long long*)(wsm + 2048);
        #pragma unroll
        for (int i = 0; i < 4; ++i) {
            const int idx = t + 256 * i;
            rowm[qmb[idx] * Sn + qms[idx]] = 1;
            atomicOr(&colbits[kmb[idx] * NT + (kms[idx] >> 6)], 1ull << (kms[idx] & 63));
        }
    }

    unsigned short* out = blob + ((size_t)((b * Hn + h) * NT + kt)) * TILE_SH;
    const int key = t >> 2, dg = (t & 3) * 16;
    {   // K tile rows [key][d], bf16
        const float* kp = K + (((size_t)b * Sn + kt * TK + key) * Hn + h) * Dn + dg;
        uint2 w[4];
        #pragma unroll
        for (int j = 0; j < 4; ++j) {
            float4 v = *(const float4*)(kp + j * 4);
            w[j].x = pk2(v.x, v.y); w[j].y = pk2(v.z, v.w);
        }
        uint2* o = (uint2*)&out[key * LDE + dg];
        #pragma unroll
        for (int j = 0; j < 4; ++j) o[j] = w[j];
    }
    {   // V rows -> f32 LDS transposed
        const float* vp = V + (((size_t)b * Hn + h) * Sn + kt * TK + key) * Dn + dg;
        #pragma unroll
        for (int j = 0; j < 4; ++j) {
            float4 v = *(const float4*)(vp + j * 4);
            Vl[(dg + j * 4 + 0) * 65 + key] = v.x;
            Vl[(dg + j * 4 + 1) * 65 + key] = v.y;
            Vl[(dg + j * 4 + 2) * 65 + key] = v.z;
            Vl[(dg + j * 4 + 3) * 65 + key] = v.w;
        }
    }
    __syncthreads();
    {   // V^T rows [d][key] -> bf16 blob
        const int d = t >> 2, kc = (t & 3) * 16;
        float tmp[16];
        #pragma unroll
        for (int i = 0; i < 16; ++i) tmp[i] = Vl[d * 65 + kc + i];
        uint2* o = (uint2*)&out[64 * LDE + d * LDE + kc];
        #pragma unroll
        for (int j = 0; j < 4; ++j) {
            uint2 w; w.x = pk2(tmp[j * 4 + 0], tmp[j * 4 + 1]);
            w.y = pk2(tmp[j * 4 + 2], tmp[j * 4 + 3]);
            o[j] = w;
        }
    }
}

// ---- main kernel: S^T = K·Q^T (32x32x16), P chained in-register into P·V ----
// R5-verified single-buffer 2-barrier structure; now 4 waves/block x 32 q/wave
// -> 16 waves/CU so other blocks' waves cover each block's barrier drain.
// sigma-cancellation: P keeps its natural C-layout key enumeration; V B-frags
// are loaded with the IDENTICAL enumeration, so the HW k-slot mapping cancels.
__global__ __launch_bounds__(256, 4) void attn4(
    const float* __restrict__ Q, const unsigned short* __restrict__ blob,
    const unsigned char* __restrict__ rowm,
    const unsigned long long* __restrict__ colbits,
    float* __restrict__ Out)
{
    __shared__ unsigned short KV[TILE_SH];   // [K 64x72 | Vt 64x72]
    const int t = threadIdx.x;
    const int wave = t >> 6, lane = t & 63;
    const int l31 = lane & 31, q2 = lane >> 5;
    const int bh = blockIdx.x, b = bh >> 4, h = bh & 15;
    const int qb = blockIdx.y * BQ + wave * 32;   // this wave's 32 queries

    // Q B-fragments: B[k=d][n=q], lane n=l31, slot (q2,j) -> d = st*16 + q2*8 + j
    s16x8 qf[4];
    {
        const float* qp = Q + (((size_t)b * Sn + qb + l31) * Hn + h) * Dn + q2 * 8;
        #pragma unroll
        for (int st = 0; st < 4; ++st) {
            float4 a = *(const float4*)(qp + st * 16);
            float4 c = *(const float4*)(qp + st * 16 + 4);
            union { unsigned w[4]; s16x8 v; } f;
            f.w[0] = pk2(a.x * kSC, a.y * kSC);
            f.w[1] = pk2(a.z * kSC, a.w * kSC);
            f.w[2] = pk2(c.x * kSC, c.y * kSC);
            f.w[3] = pk2(c.z * kSC, c.w * kSC);
            qf[st] = f.v;
        }
    }
    const bool rmb = rowm[b * Sn + qb + l31] != 0;
    const float rmONE = rmb ? 1.0f : 0.0f;
    const unsigned rmKEEP = rmb ? 0u : 0xFFFFFFFFu;

    f32x16 O[2];
    #pragma unroll
    for (int dt = 0; dt < 2; ++dt)
        #pragma unroll
        for (int i = 0; i < 16; ++i) O[dt][i] = 0.0f;
    float lsum = 0.0f;

    const unsigned short* tile0 = blob + (size_t)bh * NT * TILE_SH;

    for (int kt = 0; kt < NT; ++kt) {
        __syncthreads();   // prior tile's LDS reads done before restaging
        {   // stage 18432 B = 4 x (256 x 16 B) + tail 2048 B, async direct-to-LDS
            const GLOBAL_AS unsigned int* g =
                (const GLOBAL_AS unsigned int*)(tile0 + (size_t)kt * TILE_SH);
            LDS_AS unsigned int* l = (LDS_AS unsigned int*)KV;
            #pragma unroll
            for (int j = 0; j < 4; ++j)
                __builtin_amdgcn_global_load_lds(g + j * 1024 + t * 4,
                                                 l + j * 1024 + t * 4, 16, 0, 0);
            if (t < 128)   // waves 0,1: wave-uniform tail
                __builtin_amdgcn_global_load_lds(g + 4096 + t * 4,
                                                 l + 4096 + t * 4, 16, 0, 0);
        }
        const unsigned long long cmask = colbits[b * NT + kt];
        __syncthreads();

        #pragma unroll
        for (int ct = 0; ct < 2; ++ct) {
            // K A-frags: A[m=key][k=d], lane m = ct*32+l31, slot (q2,j) -> d = st*16+q2*8+j
            s16x8 kf[4];
            #pragma unroll
            for (int st = 0; st < 4; ++st)
                kf[st] = *(const s16x8*)&KV[(ct * 32 + l31) * LDE + st * 16 + q2 * 8];
            const unsigned ncm = ~(((unsigned)(cmask >> (ct * 32))) >> (q2 * 4));

            f32x16 sc;
            #pragma unroll
            for (int i = 0; i < 16; ++i) sc[i] = 0.0f;
            #pragma unroll
            for (int st = 0; st < 4; ++st)
                sc = __builtin_amdgcn_mfma_f32_32x32x16_bf16(kf[st], qf[st], sc, 0, 0, 0);

            // S^T C-layout (HW-verified): key_in_block = (reg&3)+8*(reg>>2)+4*q2, q=l31
            const unsigned keep = ncm & rmKEEP;
            unsigned u[8];
            #pragma unroll
            for (int c = 0; c < 4; ++c) {
                float p[4];
                #pragma unroll
                for (int j = 0; j < 4; ++j) {
                    float e = EXP2F(sc[4 * c + j]);
                    unsigned m = (unsigned)__builtin_amdgcn_sbfe((int)keep, 8 * c + j, 1);
                    p[j] = __uint_as_float(__float_as_uint(e) & m) + rmONE;
                }
                lsum += (p[0] + p[1]) + (p[2] + p[3]);
                u[2 * c]     = pk2(p[0], p[1]);
                u[2 * c + 1] = pk2(p[2], p[3]);
            }
            s16x8 P[2];
            union { unsigned w[4]; s16x8 v; } f0, f1;
            f0.w[0] = u[0]; f0.w[1] = u[1]; f0.w[2] = u[2]; f0.w[3] = u[3];
            f1.w[0] = u[4]; f1.w[1] = u[5]; f1.w[2] = u[6]; f1.w[3] = u[7];
            P[0] = f0.v;   // slot (q2,j') -> key 16*0 + 8*(j'>>2) + 4*q2 + (j'&3)
            P[1] = f1.v;   // slot (q2,j') -> key 16*1 + 8*(j'>>2) + 4*q2 + (j'&3)

            // P·V: B = V^T with the SAME slot->key enumeration as P:
            // slot (q2,j') -> key = ct*32 + ch*16 + 8*(j'>>2) + 4*q2 + (j'&3)
            const unsigned short* Vt = &KV[64 * LDE];
            #pragma unroll
            for (int dt = 0; dt < 2; ++dt)
                #pragma unroll
                for (int ch = 0; ch < 2; ++ch) {
                    const int base = (dt * 32 + l31) * LDE + ct * 32 + ch * 16 + q2 * 4;
                    s16x4 lo = *(const s16x4*)&Vt[base];       // keys +{0..3}
                    s16x4 hi = *(const s16x4*)&Vt[base + 8];   // keys +8+{0..3}
                    s16x8 vf = __builtin_shufflevector(lo, hi, 0, 1, 2, 3, 4, 5, 6, 7);
                    O[dt] = __builtin_amdgcn_mfma_f32_32x32x16_bf16(P[ch], vf, O[dt], 0, 0, 0);
                }
        }
    }

    // epilogue: lane l31 holds lsum for q=l31 over half the keys; halves are lanes l, l^32.
    const float invs = 1.0f / (lsum + __shfl_xor(lsum, 32, 64));
    float* op = Out + ((size_t)(b * Hn + h)) * Sn * Dn;
    #pragma unroll
    for (int reg = 0; reg < 16; ++reg) {
        const int qrow = (reg & 3) + 8 * (reg >> 2) + 4 * q2;
        const float invl = __shfl(invs, qrow, 64);   // value for q=qrow lives in lane qrow
        const int q = qb + qrow;
        #pragma unroll
        for (int dt = 0; dt < 2; ++dt)
            op[(size_t)q * Dn + dt * 32 + l31] = O[dt][reg] * invl;
    }
}

extern "C" void kernel_launch(void* const* d_in, const int* in_sizes, int n_in,
                              void* d_out, int out_size, void* d_ws, size_t ws_size,
                              hipStream_t stream) {
    (void)in_sizes; (void)n_in; (void)out_size; (void)ws_size;
    const float* Q = (const float*)d_in[0];
    const float* K = (const float*)d_in[1];
    const float* V = (const float*)d_in[2];
    const int* qmb = (const int*)d_in[3];
    const int* qms = (const int*)d_in[4];
    const int* kmb = (const int*)d_in[5];
    const int* kms = (const int*)d_in[6];
    float* Out = (float*)d_out;

    unsigned short* blob = (unsigned short*)d_ws;
    unsigned int* wsm = (unsigned int*)(void*)((char*)d_ws + ROWM_OFF);
    const unsigned char* rowm = (const unsigned char*)wsm;
    const unsigned long long* colbits = (const unsigned long long*)(wsm + 2048);

    convert3<<<dim3(NT, Hn, Bn), 256, 0, stream>>>(K, V, blob, qmb, qms, kmb, kms, wsm);
    attn4<<<dim3(Bn * Hn, Sn / BQ), 256, 0, stream>>>(Q, blob, rowm, colbits, Out);
}

// Round 9
// 186.124 us; speedup vs baseline: 1.4188x; 1.0441x over previous
//
#include <hip/hip_runtime.h>
#include <stdint.h>

#define GLOBAL_AS __attribute__((address_space(1)))
#define LDS_AS __attribute__((address_space(3)))

namespace {
constexpr int Bn = 8, Sn = 1024, Hn = 16, Dn = 64, Mn = 1024;
constexpr int BQ = 128;                 // queries per block (32 per wave, 4 waves)
constexpr int TK = 64;                  // keys per tile
constexpr int NT = Sn / TK;             // 16 tiles
constexpr int LDE = 72;                 // padded leading dim (shorts); 144B rows -> 16B aligned
constexpr int TILE_SH = 2 * 64 * LDE;   // shorts per (K | Vt) tile = 9216 (18432 B)
constexpr size_t BLOB_BYTES = (size_t)Bn * Hn * NT * TILE_SH * 2;   // 37,748,736
constexpr size_t ROWM_OFF = BLOB_BYTES;                             // 8192 B (rowm) + 1024 B (colbits)
constexpr float kSC = 0.125f * 1.4426950408889634f;  // 1/sqrt(D) * log2(e) folded into Q
constexpr float kBIAS = -1e8f;          // col-mask bias in exp2 domain: exp2f(-1e8) == 0

using f32x16 = __attribute__((ext_vector_type(16))) float;
using s16x8 = __attribute__((ext_vector_type(8))) short;

// RNE f32->bf16 pair pack; native __bf16 cast lowers to v_cvt_pk_bf16_f32 on gfx950
__device__ inline unsigned pk2(float a, float b) {
    union { __bf16 h[2]; unsigned u; } x;
    x.h[0] = (__bf16)a; x.h[1] = (__bf16)b;
    return x.u;
}

#if __has_builtin(__builtin_amdgcn_exp2f)
#define EXP2F __builtin_amdgcn_exp2f
#else
#define EXP2F exp2f
#endif
}  // namespace

// ---------------- masks: zero ALL 2304 u32 (rowm 2048 + colbits 256), then fill ----------------
__global__ __launch_bounds__(1024) void masks_k(
    const int* __restrict__ qmb, const int* __restrict__ qms,
    const int* __restrict__ kmb, const int* __restrict__ kms,
    unsigned int* __restrict__ wsm)
{
    const int t = threadIdx.x;
    wsm[t] = 0; wsm[t + 1024] = 0;
    if (t < 256) wsm[t + 2048] = 0;
    __syncthreads();
    unsigned char* rowm = (unsigned char*)wsm;
    unsigned long long* colbits = (unsigned long long*)(wsm + 2048);
    rowm[qmb[t] * Sn + qms[t]] = 1;
    atomicOr(&colbits[kmb[t] * NT + (kms[t] >> 6)], 1ull << (kms[t] & 63));
}

// ---- precompute: bf16 K rows (+bias short at d=64) and pre-permuted V^T tiles ----
__global__ __launch_bounds__(256) void convert4(
    const float* __restrict__ K, const float* __restrict__ V,
    unsigned short* __restrict__ blob,
    const unsigned long long* __restrict__ colbits)
{
    __shared__ float Vl[64 * 65];   // f32 transpose buffer, stride 65 words
    const int t = threadIdx.x;
    const int kt = blockIdx.x, h = blockIdx.y, b = blockIdx.z;
    unsigned short* out = blob + ((size_t)((b * Hn + h) * NT + kt)) * TILE_SH;
    const unsigned long long cb = colbits[b * NT + kt];

    const int key = t >> 2, dg = (t & 3) * 16;
    {   // K tile rows [key][d], bf16
        const float* kp = K + (((size_t)b * Sn + kt * TK + key) * Hn + h) * Dn + dg;
        uint2 w[4];
        #pragma unroll
        for (int j = 0; j < 4; ++j) {
            float4 v = *(const float4*)(kp + j * 4);
            w[j].x = pk2(v.x, v.y); w[j].y = pk2(v.z, v.w);
        }
        uint2* o = (uint2*)&out[key * LDE + dg];
        #pragma unroll
        for (int j = 0; j < 4; ++j) o[j] = w[j];
    }
    if ((t & 3) == 3) {   // pad shorts 64..71: [bias, 0, 0, 0, 0, 0, 0, 0]
        const float bias = ((cb >> key) & 1ull) ? kBIAS : 0.0f;
        uint2 w; w.x = pk2(bias, 0.0f); w.y = 0u;
        *(uint2*)&out[key * LDE + 64] = w;
        *(uint2*)&out[key * LDE + 68] = (uint2){0u, 0u};
    }
    {   // V rows -> f32 LDS transposed
        const float* vp = V + (((size_t)b * Hn + h) * Sn + kt * TK + key) * Dn + dg;
        #pragma unroll
        for (int j = 0; j < 4; ++j) {
            float4 v = *(const float4*)(vp + j * 4);
            Vl[(dg + j * 4 + 0) * 65 + key] = v.x;
            Vl[(dg + j * 4 + 1) * 65 + key] = v.y;
            Vl[(dg + j * 4 + 2) * 65 + key] = v.z;
            Vl[(dg + j * 4 + 3) * 65 + key] = v.w;
        }
    }
    __syncthreads();
    {   // V^T rows [d][key], keys pre-permuted {0-3,8-11,4-7,12-15} per 16-group
        const int d = t >> 2, kc = (t & 3) * 16;
        float tmp[16];
        #pragma unroll
        for (int i = 0; i < 16; ++i) tmp[i] = Vl[d * 65 + kc + i];
        const int perm[16] = {0, 1, 2, 3, 8, 9, 10, 11, 4, 5, 6, 7, 12, 13, 14, 15};
        uint2* o = (uint2*)&out[64 * LDE + d * LDE + kc];
        #pragma unroll
        for (int j = 0; j < 4; ++j) {
            uint2 w;
            w.x = pk2(tmp[perm[4 * j + 0]], tmp[perm[4 * j + 1]]);
            w.y = pk2(tmp[perm[4 * j + 2]], tmp[perm[4 * j + 3]]);
            o[j] = w;
        }
    }
}

// ---- main kernel: S^T = K·Q^T (5x 32x32x16; 5th step injects col-bias), in-register P -> P·V ----
// sigma-cancellation: P keeps its natural C-layout key enumeration; V^T blob is
// pre-permuted to the IDENTICAL enumeration (single b128 per B-frag).
// Masking is fully folded into the MFMA: bias slot (q2=0,j=0) of K-frag 5 carries
// -1e8 for col-masked keys; Q weight there is (row-masked ? 0 : 1), and row-masked
// lanes have Q scaled by 0 -> s'=0 -> p=1 uniform (matches ref exactly).
__global__ __launch_bounds__(256, 4) void attn5(
    const float* __restrict__ Q, const unsigned short* __restrict__ blob,
    const unsigned char* __restrict__ rowm,
    float* __restrict__ Out)
{
    __shared__ unsigned short KV[TILE_SH];   // [K 64x72 | Vt 64x72]
    const int t = threadIdx.x;
    const int wave = t >> 6, lane = t & 63;
    const int l31 = lane & 31, q2 = lane >> 5;
    const int bh = blockIdx.x, b = bh >> 4, h = bh & 15;
    const int qb = blockIdx.y * BQ + wave * 32;   // this wave's 32 queries

    const bool rmb = rowm[b * Sn + qb + l31] != 0;
    const float qscale = rmb ? 0.0f : kSC;

    // Q B-fragments: B[k=d][n=q], lane n=l31, slot (q2,j) -> d = st*16 + q2*8 + j
    s16x8 qf[5];
    {
        const float* qp = Q + (((size_t)b * Sn + qb + l31) * Hn + h) * Dn + q2 * 8;
        #pragma unroll
        for (int st = 0; st < 4; ++st) {
            float4 a = *(const float4*)(qp + st * 16);
            float4 c = *(const float4*)(qp + st * 16 + 4);
            union { unsigned w[4]; s16x8 v; } f;
            f.w[0] = pk2(a.x * qscale, a.y * qscale);
            f.w[1] = pk2(a.z * qscale, a.w * qscale);
            f.w[2] = pk2(c.x * qscale, c.y * qscale);
            f.w[3] = pk2(c.z * qscale, c.w * qscale);
            qf[st] = f.v;
        }
        union { unsigned w[4]; s16x8 v; } f5;   // bias weight at slot (q2=0, j=0)
        f5.w[0] = (q2 == 0) ? pk2(rmb ? 0.0f : 1.0f, 0.0f) : 0u;
        f5.w[1] = 0u; f5.w[2] = 0u; f5.w[3] = 0u;
        qf[4] = f5.v;
    }

    f32x16 O[2];
    #pragma unroll
    for (int dt = 0; dt < 2; ++dt)
        #pragma unroll
        for (int i = 0; i < 16; ++i) O[dt][i] = 0.0f;
    float lsum = 0.0f;

    const unsigned short* tile0 = blob + (size_t)bh * NT * TILE_SH;

    for (int kt = 0; kt < NT; ++kt) {
        __syncthreads();   // prior tile's LDS reads done before restaging
        {   // stage 18432 B = 4 x (256 x 16 B) + tail 2048 B, async direct-to-LDS
            const GLOBAL_AS unsigned int* g =
                (const GLOBAL_AS unsigned int*)(tile0 + (size_t)kt * TILE_SH);
            LDS_AS unsigned int* l = (LDS_AS unsigned int*)KV;
            #pragma unroll
            for (int j = 0; j < 4; ++j)
                __builtin_amdgcn_global_load_lds(g + j * 1024 + t * 4,
                                                 l + j * 1024 + t * 4, 16, 0, 0);
            if (t < 128)   // waves 0,1: wave-uniform tail
                __builtin_amdgcn_global_load_lds(g + 4096 + t * 4,
                                                 l + 4096 + t * 4, 16, 0, 0);
        }
        __syncthreads();

        #pragma unroll
        for (int ct = 0; ct < 2; ++ct) {
            // K A-frags: A[m=key][k=d], lane m = ct*32+l31, slot (q2,j) -> d = st*16+q2*8+j.
            // st=4 covers d=64..79: q2=0 j=0 is the bias; all other slots pair with
            // zero Q weights (row pads / next-row overrun are finite, weighted 0).
            s16x8 kf[5];
            #pragma unroll
            for (int st = 0; st < 5; ++st)
                kf[st] = *(const s16x8*)&KV[(ct * 32 + l31) * LDE + st * 16 + q2 * 8];

            f32x16 sc;
            #pragma unroll
            for (int i = 0; i < 16; ++i) sc[i] = 0.0f;
            #pragma unroll
            for (int st = 0; st < 5; ++st)
                sc = __builtin_amdgcn_mfma_f32_32x32x16_bf16(kf[st], qf[st], sc, 0, 0, 0);

            // S^T C-layout (HW-verified): key_in_block = (reg&3)+8*(reg>>2)+4*q2, q=l31.
            // Masking already applied inside sc -> p = exp2(sc) directly.
            unsigned u[8];
            #pragma unroll
            for (int c = 0; c < 4; ++c) {
                float p0 = EXP2F(sc[4 * c + 0]);
                float p1 = EXP2F(sc[4 * c + 1]);
                float p2 = EXP2F(sc[4 * c + 2]);
                float p3 = EXP2F(sc[4 * c + 3]);
                lsum += (p0 + p1) + (p2 + p3);
                u[2 * c]     = pk2(p0, p1);
                u[2 * c + 1] = pk2(p2, p3);
            }
            s16x8 P[2];
            union { unsigned w[4]; s16x8 v; } f0, f1;
            f0.w[0] = u[0]; f0.w[1] = u[1]; f0.w[2] = u[2]; f0.w[3] = u[3];
            f1.w[0] = u[4]; f1.w[1] = u[5]; f1.w[2] = u[6]; f1.w[3] = u[7];
            P[0] = f0.v;   // slot (q2,j') -> key 16*0 + 8*(j'>>2) + 4*q2 + (j'&3)
            P[1] = f1.v;   // slot (q2,j') -> key 16*1 + 8*(j'>>2) + 4*q2 + (j'&3)

            // P·V: B-frag = one b128 from the pre-permuted V^T (same slot->key enum as P)
            const unsigned short* Vt = &KV[64 * LDE];
            #pragma unroll
            for (int dt = 0; dt < 2; ++dt)
                #pragma unroll
                for (int ch = 0; ch < 2; ++ch) {
                    s16x8 vf = *(const s16x8*)&Vt[(dt * 32 + l31) * LDE + ct * 32 + ch * 16 + q2 * 8];
                    O[dt] = __builtin_amdgcn_mfma_f32_32x32x16_bf16(P[ch], vf, O[dt], 0, 0, 0);
                }
        }
    }

    // epilogue: lane l31 holds lsum for q=l31 over half the keys; halves are lanes l, l^32.
    const float invs = 1.0f / (lsum + __shfl_xor(lsum, 32, 64));
    float* op = Out + ((size_t)(b * Hn + h)) * Sn * Dn;
    #pragma unroll
    for (int reg = 0; reg < 16; ++reg) {
        const int qrow = (reg & 3) + 8 * (reg >> 2) + 4 * q2;
        const float invl = __shfl(invs, qrow, 64);   // value for q=qrow lives in lane qrow
        const int q = qb + qrow;
        #pragma unroll
        for (int dt = 0; dt < 2; ++dt)
            op[(size_t)q * Dn + dt * 32 + l31] = O[dt][reg] * invl;
    }
}

extern "C" void kernel_launch(void* const* d_in, const int* in_sizes, int n_in,
                              void* d_out, int out_size, void* d_ws, size_t ws_size,
                              hipStream_t stream) {
    (void)in_sizes; (void)n_in; (void)out_size; (void)ws_size;
    const float* Q = (const float*)d_in[0];
    const float* K = (const float*)d_in[1];
    const float* V = (const float*)d_in[2];
    const int* qmb = (const int*)d_in[3];
    const int* qms = (const int*)d_in[4];
    const int* kmb = (const int*)d_in[5];
    const int* kms = (const int*)d_in[6];
    float* Out = (float*)d_out;

    unsigned short* blob = (unsigned short*)d_ws;
    unsigned int* wsm = (unsigned int*)(void*)((char*)d_ws + ROWM_OFF);
    const unsigned char* rowm = (const unsigned char*)wsm;
    const unsigned long long* colbits = (const unsigned long long*)(wsm + 2048);

    masks_k<<<1, 1024, 0, stream>>>(qmb, qms, kmb, kms, wsm);
    convert4<<<dim3(NT, Hn, Bn), 256, 0, stream>>>(K, V, blob, colbits);
    attn5<<<dim3(Bn * Hn, Sn / BQ), 256, 0, stream>>>(Q, blob, rowm, Out);
}